// Round 1
// baseline (32.486 us; speedup 1.0000x reference)
//
#include <hip/hip_runtime.h>

#define N_PTS 2048
#define T_FR  2
#define IMG   128
#define HW    (IMG * IMG)
#define BLOCK 512
#define WAVES 8
#define GPW   (N_PTS / WAVES)   // gaussians per wave = 256

#if defined(__has_builtin)
#if __has_builtin(__builtin_amdgcn_exp2f)
#define FAST_EXP2(x) __builtin_amdgcn_exp2f(x)
#endif
#endif
#ifndef FAST_EXP2
#define FAST_EXP2(x) exp2f(x)
#endif

__device__ __forceinline__ float sigmoid_fast(float x) {
    return 1.0f / (1.0f + FAST_EXP2(-1.44269504089f * x));
}

// tanh(x) = 1 - 2/(exp2(2x*log2e)+1); exact limits at +-inf, ~1e-7 rel err
__device__ __forceinline__ float tanh_fast(float x) {
    return 1.0f - 2.0f / (FAST_EXP2(2.88539008178f * x) + 1.0f);
}

__launch_bounds__(BLOCK, 4)
__global__ void GaussianImage_Cholesky_render(const float* __restrict__ xyz,
                                              const float* __restrict__ chol,
                                              const float* __restrict__ opa,
                                              const float* __restrict__ feat,
                                              const float* __restrict__ tv,
                                              float* __restrict__ out) {
    // sA[g] = {mx, my, a', b2'}   sB[g] = {c', op*cr, op*cg, op*cb}
    // where a',b2',c' already include the -0.5*log2(e) factor so the
    // inner loop is w = exp2(a'*dx^2 + b2'*dx*dy + c'*dy^2).
    __shared__ float4 sA[N_PTS];
    __shared__ float4 sB[N_PTS];
    __shared__ float red[BLOCK * 3];

    const int bid  = blockIdx.x;
    const int t    = bid >> 8;          // 256 tiles per frame
    const int tile = bid & 255;
    const int h0   = (tile >> 4) << 3;  // 16x16 grid of 8x8 tiles
    const int w0   = (tile & 15) << 3;
    const int tid  = threadIdx.x;

    const float tt = tv[t];
    const float t2 = tt * tt;
    const float K  = -0.72134752044f;   // -0.5 * log2(e)

    // ---- Phase 1: per-frame gaussian params -> LDS (block-redundant, cheap) ----
    for (int g = tid; g < N_PTS; g += BLOCK) {
        float sx = fmaf(t2, xyz[2 * N_PTS * 2 + g * 2 + 0],
                   fmaf(tt, xyz[N_PTS * 2 + g * 2 + 0], xyz[g * 2 + 0]));
        float sy = fmaf(t2, xyz[2 * N_PTS * 2 + g * 2 + 1],
                   fmaf(tt, xyz[N_PTS * 2 + g * 2 + 1], xyz[g * 2 + 1]));
        float mx = 64.0f * (tanh_fast(sx) + 1.0f);   // 0.5*(tanh+1)*W, W=128
        float my = 64.0f * (tanh_fast(sy) + 1.0f);

        float l0 = fmaf(t2, chol[2 * N_PTS * 3 + g * 3 + 0],
                   fmaf(tt, chol[N_PTS * 3 + g * 3 + 0], chol[g * 3 + 0])) + 0.5f;
        float l1 = fmaf(t2, chol[2 * N_PTS * 3 + g * 3 + 1],
                   fmaf(tt, chol[N_PTS * 3 + g * 3 + 1], chol[g * 3 + 1]));
        float l2 = fmaf(t2, chol[2 * N_PTS * 3 + g * 3 + 2],
                   fmaf(tt, chol[N_PTS * 3 + g * 3 + 2], chol[g * 3 + 2])) + 0.5f;

        float s11 = l0 * l0;
        float s12 = l0 * l1;
        float s22 = fmaf(l1, l1, l2 * l2);
        float det = fmaf(s11, s22, -s12 * s12);
        float Kinv = K / det;
        float ap  = s22 * Kinv;           // K * (s22/det)
        float b2p = -2.0f * s12 * Kinv;   // K * 2 * (-s12/det)
        float cp  = s11 * Kinv;           // K * (s11/det)

        float po = fmaf(t2, opa[2 * N_PTS + g], fmaf(tt, opa[N_PTS + g], opa[g]));
        float op = sigmoid_fast(po);
        float cr = op * sigmoid_fast(feat[g * 3 + 0]);
        float cg = op * sigmoid_fast(feat[g * 3 + 1]);
        float cb = op * sigmoid_fast(feat[g * 3 + 2]);

        sA[g] = make_float4(mx, my, ap, b2p);
        sB[g] = make_float4(cp, cr, cg, cb);
    }
    __syncthreads();

    // ---- Phase 2: each wave sweeps its 256-gaussian chunk over the 8x8 tile ----
    const int lane = tid & 63;
    const int wv   = tid >> 6;
    const float px = (float)(w0 + (lane & 7)) + 0.5f;
    const float py = (float)(h0 + (lane >> 3)) + 0.5f;

    float accr = 0.0f, accg = 0.0f, accb = 0.0f;
    const int base = wv * GPW;
#pragma unroll 4
    for (int i = 0; i < GPW; ++i) {
        float4 A = sA[base + i];   // broadcast ds_read_b128, conflict-free
        float4 B = sB[base + i];
        float dx = A.x - px;
        float dy = A.y - py;
        float t1 = fmaf(A.w, dy, A.z * dx);          // a'*dx + b2'*dy
        float q  = fmaf(B.x * dy, dy, t1 * dx);      // ... + c'*dy^2
        float wgt = FAST_EXP2(q);
        accr = fmaf(wgt, B.y, accr);
        accg = fmaf(wgt, B.z, accg);
        accb = fmaf(wgt, B.w, accb);
    }

    red[tid * 3 + 0] = accr;
    red[tid * 3 + 1] = accg;
    red[tid * 3 + 2] = accb;
    __syncthreads();

    // ---- Phase 3: deterministic fixed-order reduce over the 8 waves ----
    if (tid < 64) {
        float rr = 0.0f, gg = 0.0f, bb = 0.0f;
        for (int w8 = 0; w8 < WAVES; ++w8) {
            rr += red[(w8 * 64 + tid) * 3 + 0];
            gg += red[(w8 * 64 + tid) * 3 + 1];
            bb += red[(w8 * 64 + tid) * 3 + 2];
        }
        const int h   = h0 + (tid >> 3);
        const int w   = w0 + (tid & 7);
        const int pix = h * IMG + w;
        out[(t * 3 + 0) * HW + pix] = fminf(fmaxf(rr, 0.0f), 1.0f);
        out[(t * 3 + 1) * HW + pix] = fminf(fmaxf(gg, 0.0f), 1.0f);
        out[(t * 3 + 2) * HW + pix] = fminf(fmaxf(bb, 0.0f), 1.0f);
    }
}

extern "C" void kernel_launch(void* const* d_in, const int* in_sizes, int n_in,
                              void* d_out, int out_size, void* d_ws, size_t ws_size,
                              hipStream_t stream) {
    const float* xyz  = (const float*)d_in[0];  // [3, N, 2]
    const float* chol = (const float*)d_in[1];  // [3, N, 3]
    const float* opa  = (const float*)d_in[2];  // [3, N, 1]
    const float* feat = (const float*)d_in[3];  // [N, 3]
    const float* tv   = (const float*)d_in[4];  // [T]

    GaussianImage_Cholesky_render<<<T_FR * 256, BLOCK, 0, stream>>>(
        xyz, chol, opa, feat, tv, (float*)d_out);
}

// Round 2
// 28.229 us; speedup vs baseline: 1.1508x; 1.1508x over previous
//
#include <hip/hip_runtime.h>

#define N_PTS  2048
#define T_FR   2
#define IMG    128
#define HW     (IMG * IMG)
#define TILE   8
#define RBLOCK 256              // 4 waves
#define RWAVES 4
#define CHUNK  512              // gaussians per compaction chunk
#define NCHUNK (N_PTS / CHUNK)  // 4
// exp2 cutoff at 2^-26: Q = 26 / (0.5*log2(e)) in original q units
#define QCUT   36.043653f

#if defined(__has_builtin)
#if __has_builtin(__builtin_amdgcn_exp2f)
#define FAST_EXP2(x) __builtin_amdgcn_exp2f(x)
#endif
#endif
#ifndef FAST_EXP2
#define FAST_EXP2(x) exp2f(x)
#endif

__device__ __forceinline__ float sigmoid_fast(float x) {
    return 1.0f / (1.0f + FAST_EXP2(-1.44269504089f * x));
}
__device__ __forceinline__ float tanh_fast(float x) {
    return 1.0f - 2.0f / (FAST_EXP2(2.88539008178f * x) + 1.0f);
}

// d_ws layout: pA[T*N] float4 | pB[T*N] float4 | rad[T*N] float2
__global__ void gi_precompute(const float* __restrict__ xyz,
                              const float* __restrict__ chol,
                              const float* __restrict__ opa,
                              const float* __restrict__ feat,
                              const float* __restrict__ tv,
                              float4* __restrict__ pA,
                              float4* __restrict__ pB,
                              float2* __restrict__ rad) {
    const int idx = blockIdx.x * blockDim.x + threadIdx.x;
    if (idx >= T_FR * N_PTS) return;
    const int t = idx >> 11;            // / N_PTS
    const int g = idx & (N_PTS - 1);
    const float tt = tv[t];
    const float t2 = tt * tt;
    const float K  = -0.72134752044f;   // -0.5 * log2(e)

    float sx = fmaf(t2, xyz[2 * N_PTS * 2 + g * 2 + 0],
               fmaf(tt, xyz[N_PTS * 2 + g * 2 + 0], xyz[g * 2 + 0]));
    float sy = fmaf(t2, xyz[2 * N_PTS * 2 + g * 2 + 1],
               fmaf(tt, xyz[N_PTS * 2 + g * 2 + 1], xyz[g * 2 + 1]));
    float mx = 64.0f * (tanh_fast(sx) + 1.0f);
    float my = 64.0f * (tanh_fast(sy) + 1.0f);

    float l0 = fmaf(t2, chol[2 * N_PTS * 3 + g * 3 + 0],
               fmaf(tt, chol[N_PTS * 3 + g * 3 + 0], chol[g * 3 + 0])) + 0.5f;
    float l1 = fmaf(t2, chol[2 * N_PTS * 3 + g * 3 + 1],
               fmaf(tt, chol[N_PTS * 3 + g * 3 + 1], chol[g * 3 + 1]));
    float l2 = fmaf(t2, chol[2 * N_PTS * 3 + g * 3 + 2],
               fmaf(tt, chol[N_PTS * 3 + g * 3 + 2], chol[g * 3 + 2])) + 0.5f;

    float s11 = l0 * l0;
    float s12 = l0 * l1;
    float s22 = fmaf(l1, l1, l2 * l2);
    float det = fmaf(s11, s22, -s12 * s12);
    float Kinv = K / det;
    float ap  = s22 * Kinv;
    float b2p = -2.0f * s12 * Kinv;
    float cp  = s11 * Kinv;

    float po = fmaf(t2, opa[2 * N_PTS + g], fmaf(tt, opa[N_PTS + g], opa[g]));
    float op = sigmoid_fast(po);
    float cr = op * sigmoid_fast(feat[g * 3 + 0]);
    float cg = op * sigmoid_fast(feat[g * 3 + 1]);
    float cb = op * sigmoid_fast(feat[g * 3 + 2]);

    pA[idx]  = make_float4(mx, my, ap, b2p);
    pB[idx]  = make_float4(cp, cr, cg, cb);
    rad[idx] = make_float2(sqrtf(QCUT * s11), sqrtf(QCUT * s22));
}

__launch_bounds__(RBLOCK, 4)
__global__ void gi_render(const float4* __restrict__ pA,
                          const float4* __restrict__ pB,
                          const float2* __restrict__ rad,
                          float* __restrict__ out) {
    __shared__ float4 sA[CHUNK];
    __shared__ float4 sB[CHUNK];
    __shared__ int    sCnt;
    __shared__ float  red[RBLOCK * 3];

    const int bid  = blockIdx.x;
    const int t    = bid >> 8;          // 256 tiles per frame
    const int tile = bid & 255;
    const int h0   = (tile >> 4) << 3;
    const int w0   = (tile & 15) << 3;
    const int tid  = threadIdx.x;
    const int lane = tid & 63;
    const int wv   = tid >> 6;

    const float cx = (float)w0 + 4.0f;  // tile center (pixel-center coords span +-3.5)
    const float cy = (float)h0 + 4.0f;
    const float px = (float)(w0 + (lane & 7)) + 0.5f;
    const float py = (float)(h0 + (lane >> 3)) + 0.5f;
    const int   base = t * N_PTS;

    float accr = 0.0f, accg = 0.0f, accb = 0.0f;

    for (int c = 0; c < NCHUNK; ++c) {
        // ---- deterministic ballot-compaction by wave 0 (index order preserved) ----
        if (wv == 0) {
            int cnt = 0;
#pragma unroll
            for (int j = 0; j < CHUNK / 64; ++j) {
                const int g = base + c * CHUNK + j * 64 + lane;
                float4 A = pA[g];
                float2 R = rad[g];
                bool hit = (fabsf(A.x - cx) <= R.x + 3.5f) &&
                           (fabsf(A.y - cy) <= R.y + 3.5f);
                unsigned long long m = __ballot(hit);
                if (hit) {
                    int pos = cnt + __popcll(m & ((1ull << lane) - 1ull));
                    sA[pos] = A;
                    sB[pos] = pB[g];
                }
                cnt += (int)__popcll(m);
            }
            if (lane == 0) sCnt = cnt;
        }
        __syncthreads();

        // ---- all 4 waves sweep the compacted list, lane = pixel ----
        const int L = sCnt;
        for (int i = wv; i < L; i += RWAVES) {
            float4 A = sA[i];    // broadcast ds_read_b128
            float4 B = sB[i];
            float dx = A.x - px;
            float dy = A.y - py;
            float t1 = fmaf(A.w, dy, A.z * dx);      // a'*dx + b2'*dy
            float q  = fmaf(B.x * dy, dy, t1 * dx);  // + c'*dy^2
            float wgt = FAST_EXP2(q);
            accr = fmaf(wgt, B.y, accr);
            accg = fmaf(wgt, B.z, accg);
            accb = fmaf(wgt, B.w, accb);
        }
        __syncthreads();   // protect sA/sB before next chunk's compaction
    }

    red[tid * 3 + 0] = accr;
    red[tid * 3 + 1] = accg;
    red[tid * 3 + 2] = accb;
    __syncthreads();

    if (tid < 64) {
        float rr = 0.0f, gg = 0.0f, bb = 0.0f;
        for (int w8 = 0; w8 < RWAVES; ++w8) {   // fixed order -> deterministic
            rr += red[(w8 * 64 + tid) * 3 + 0];
            gg += red[(w8 * 64 + tid) * 3 + 1];
            bb += red[(w8 * 64 + tid) * 3 + 2];
        }
        const int h   = h0 + (tid >> 3);
        const int w   = w0 + (tid & 7);
        const int pix = h * IMG + w;
        out[(t * 3 + 0) * HW + pix] = fminf(fmaxf(rr, 0.0f), 1.0f);
        out[(t * 3 + 1) * HW + pix] = fminf(fmaxf(gg, 0.0f), 1.0f);
        out[(t * 3 + 2) * HW + pix] = fminf(fmaxf(bb, 0.0f), 1.0f);
    }
}

extern "C" void kernel_launch(void* const* d_in, const int* in_sizes, int n_in,
                              void* d_out, int out_size, void* d_ws, size_t ws_size,
                              hipStream_t stream) {
    const float* xyz  = (const float*)d_in[0];  // [3, N, 2]
    const float* chol = (const float*)d_in[1];  // [3, N, 3]
    const float* opa  = (const float*)d_in[2];  // [3, N, 1]
    const float* feat = (const float*)d_in[3];  // [N, 3]
    const float* tv   = (const float*)d_in[4];  // [T]

    char* ws = (char*)d_ws;
    float4* pA  = (float4*)(ws);
    float4* pB  = (float4*)(ws + (size_t)T_FR * N_PTS * 16);
    float2* rad = (float2*)(ws + (size_t)T_FR * N_PTS * 32);

    gi_precompute<<<(T_FR * N_PTS + 255) / 256, 256, 0, stream>>>(
        xyz, chol, opa, feat, tv, pA, pB, rad);
    gi_render<<<T_FR * 256, RBLOCK, 0, stream>>>(pA, pB, rad, (float*)d_out);
}

// Round 3
// 13.828 us; speedup vs baseline: 2.3493x; 2.0415x over previous
//
#include <hip/hip_runtime.h>

#define N_PTS  2048
#define T_FR   2
#define IMG    128
#define HW     (IMG * IMG)
#define BLOCK  512
#define WAVES  8
#define SEG    256              // gaussians per wave-chunk (worst-case capacity)
// exp2 cutoff at 2^-26: q > QCUT -> weight < 2^-26 (x2048 gaussians -> <3e-5 err)
#define QCUT   36.043653f

#if defined(__has_builtin)
#if __has_builtin(__builtin_amdgcn_exp2f)
#define FAST_EXP2(x) __builtin_amdgcn_exp2f(x)
#endif
#endif
#ifndef FAST_EXP2
#define FAST_EXP2(x) exp2f(x)
#endif

__device__ __forceinline__ float sigmoid_fast(float x) {
    return 1.0f / (1.0f + FAST_EXP2(-1.44269504089f * x));
}
__device__ __forceinline__ float tanh_fast(float x) {
    return 1.0f - 2.0f / (FAST_EXP2(2.88539008178f * x) + 1.0f);
}

__launch_bounds__(BLOCK, 4)
__global__ void gi_fused(const float* __restrict__ xyz,
                         const float* __restrict__ chol,
                         const float* __restrict__ opa,
                         const float* __restrict__ feat,
                         const float* __restrict__ tv,
                         float* __restrict__ out) {
    __shared__ float4 sA[WAVES][SEG];   // {mx, my, a', b2'}
    __shared__ float4 sB[WAVES][SEG];   // {c', op*r, op*g, op*b}
    __shared__ int    sCnt[WAVES];
    __shared__ float  red[BLOCK * 3];

    const int bid  = blockIdx.x;
    const int t    = bid >> 8;          // 256 tiles per frame
    const int tile = bid & 255;
    const int h0   = (tile >> 4) << 3;
    const int w0   = (tile & 15) << 3;
    const int tid  = threadIdx.x;
    const int lane = tid & 63;
    const int wv   = tid >> 6;

    const float tt = tv[t];
    const float t2 = tt * tt;
    const float K  = -0.72134752044f;   // -0.5 * log2(e)
    const float cx = (float)w0 + 4.0f;  // tile center; pixel centers span +-3.5
    const float cy = (float)h0 + 4.0f;

    // ---- Phase 1: per-wave param compute + bbox cull + ballot compaction ----
    int cnt = 0;
#pragma unroll 4
    for (int j = 0; j < SEG / 64; ++j) {
        const int g = wv * SEG + j * 64 + lane;

        const float2 x0 = *(const float2*)&xyz[g * 2];                    // 8B-aligned
        const float2 x1 = *(const float2*)&xyz[N_PTS * 2 + g * 2];
        const float2 x2 = *(const float2*)&xyz[2 * N_PTS * 2 + g * 2];
        float mx = 64.0f * (tanh_fast(fmaf(t2, x2.x, fmaf(tt, x1.x, x0.x))) + 1.0f);
        float my = 64.0f * (tanh_fast(fmaf(t2, x2.y, fmaf(tt, x1.y, x0.y))) + 1.0f);

        float l0 = fmaf(t2, chol[2 * N_PTS * 3 + g * 3 + 0],
                   fmaf(tt, chol[N_PTS * 3 + g * 3 + 0], chol[g * 3 + 0])) + 0.5f;
        float l1 = fmaf(t2, chol[2 * N_PTS * 3 + g * 3 + 1],
                   fmaf(tt, chol[N_PTS * 3 + g * 3 + 1], chol[g * 3 + 1]));
        float l2 = fmaf(t2, chol[2 * N_PTS * 3 + g * 3 + 2],
                   fmaf(tt, chol[N_PTS * 3 + g * 3 + 2], chol[g * 3 + 2])) + 0.5f;

        float s11 = l0 * l0;
        float s12 = l0 * l1;
        float s22 = fmaf(l1, l1, l2 * l2);

        bool hit = (fabsf(mx - cx) <= sqrtf(QCUT * s11) + 3.5f) &&
                   (fabsf(my - cy) <= sqrtf(QCUT * s22) + 3.5f);
        unsigned long long m = __ballot(hit);
        if (hit) {
            float det  = fmaf(s11, s22, -s12 * s12);
            float Kinv = K / det;
            float po = fmaf(t2, opa[2 * N_PTS + g], fmaf(tt, opa[N_PTS + g], opa[g]));
            float op = sigmoid_fast(po);
            int pos = cnt + (int)__popcll(m & ((1ull << lane) - 1ull));
            sA[wv][pos] = make_float4(mx, my, s22 * Kinv, -2.0f * s12 * Kinv);
            sB[wv][pos] = make_float4(s11 * Kinv,
                                      op * sigmoid_fast(feat[g * 3 + 0]),
                                      op * sigmoid_fast(feat[g * 3 + 1]),
                                      op * sigmoid_fast(feat[g * 3 + 2]));
        }
        cnt += (int)__popcll(m);
    }
    if (lane == 0) sCnt[wv] = cnt;
    __syncthreads();

    // ---- Phase 2: each wave sweeps its own compacted segment, lane = pixel ----
    const float px = (float)(w0 + (lane & 7)) + 0.5f;
    const float py = (float)(h0 + (lane >> 3)) + 0.5f;
    const int   L  = sCnt[wv];

    float accr = 0.0f, accg = 0.0f, accb = 0.0f;
    for (int i = 0; i < L; ++i) {
        float4 A = sA[wv][i];    // broadcast ds_read_b128, conflict-free
        float4 B = sB[wv][i];
        float dx = A.x - px;
        float dy = A.y - py;
        float t1 = fmaf(A.w, dy, A.z * dx);      // a'*dx + b2'*dy
        float q  = fmaf(B.x * dy, dy, t1 * dx);  // + c'*dy^2
        float wgt = FAST_EXP2(q);
        accr = fmaf(wgt, B.y, accr);
        accg = fmaf(wgt, B.z, accg);
        accb = fmaf(wgt, B.w, accb);
    }

    red[tid * 3 + 0] = accr;
    red[tid * 3 + 1] = accg;
    red[tid * 3 + 2] = accb;
    __syncthreads();

    // ---- Phase 3: deterministic fixed-order reduce over the 8 waves ----
    if (tid < 64) {
        float rr = 0.0f, gg = 0.0f, bb = 0.0f;
#pragma unroll
        for (int w8 = 0; w8 < WAVES; ++w8) {
            rr += red[(w8 * 64 + tid) * 3 + 0];
            gg += red[(w8 * 64 + tid) * 3 + 1];
            bb += red[(w8 * 64 + tid) * 3 + 2];
        }
        const int h   = h0 + (tid >> 3);
        const int w   = w0 + (tid & 7);
        const int pix = h * IMG + w;
        out[(t * 3 + 0) * HW + pix] = fminf(fmaxf(rr, 0.0f), 1.0f);
        out[(t * 3 + 1) * HW + pix] = fminf(fmaxf(gg, 0.0f), 1.0f);
        out[(t * 3 + 2) * HW + pix] = fminf(fmaxf(bb, 0.0f), 1.0f);
    }
}

extern "C" void kernel_launch(void* const* d_in, const int* in_sizes, int n_in,
                              void* d_out, int out_size, void* d_ws, size_t ws_size,
                              hipStream_t stream) {
    const float* xyz  = (const float*)d_in[0];  // [3, N, 2]
    const float* chol = (const float*)d_in[1];  // [3, N, 3]
    const float* opa  = (const float*)d_in[2];  // [3, N, 1]
    const float* feat = (const float*)d_in[3];  // [N, 3]
    const float* tv   = (const float*)d_in[4];  // [T]

    gi_fused<<<T_FR * 256, BLOCK, 0, stream>>>(
        xyz, chol, opa, feat, tv, (float*)d_out);
}